// Round 6
// baseline (1373.827 us; speedup 1.0000x reference)
//
#include <hip/hip_runtime.h>

// ---------------------------------------------------------------------------
// TransformerBlock: B=2, L=2048, D=2048, H=16, HD=128, FF=8192.
// Dual-dtype (runtime-detected): DT=0 (f32 I/O — the ACTIVE path per rocprof)
// and DT=1 (bf16 I/O) pipelines; detector writes flag; kernels no-op unless
// flag==PID. Intermediates always bf16.
// DT=0: each f32 weight panel is pre-converted to bf16 (convw_kernel) into
// scratch (d_out until the final GEMM, h2-region for the last down chunk),
// then ALL GEMMs run gemm8 (256x256, BK=64, 8 waves, double-buffered 128KiB
// LDS, counted-vmcnt staging, raw barriers, setprio).
// Workspace (64MB + flag word): qkv[0,48) / x2[0,16) / h2[16,32) / a[32,64)
//   h,o[48,64); flag at min(64MB, ws_size-4). d_out doubles as weight scratch.
// ---------------------------------------------------------------------------

typedef __attribute__((ext_vector_type(8))) short bf16x8;
typedef __attribute__((ext_vector_type(4))) float f32x4;

__device__ __forceinline__ float b2f(unsigned short u) {
    return __uint_as_float(((unsigned int)u) << 16);
}
__device__ __forceinline__ unsigned short f2b(float f) {
    unsigned int i = __float_as_uint(f);
    i += 0x7fffu + ((i >> 16) & 1u);   // RNE
    return (unsigned short)(i >> 16);
}
// packed f32x2 -> bf16x2 (RNE), single VALU op; no builtin on gfx950
__device__ __forceinline__ unsigned int cvt_pk_bf16(float lo, float hi) {
    unsigned int r;
    asm("v_cvt_pk_bf16_f32 %0, %1, %2" : "=v"(r) : "v"(lo), "v"(hi));
    return r;
}

// async global->LDS, 16 B per lane; LDS dest is wave-uniform base + lane*16.
__device__ __forceinline__ void gload_lds16(const unsigned short* g, unsigned short* l) {
    __builtin_amdgcn_global_load_lds(
        (const __attribute__((address_space(1))) unsigned int*)g,
        (__attribute__((address_space(3))) unsigned int*)l,
        16, 0, 0);
}

// ---- typed I/O helpers: DT=1 bf16, DT=0 f32 -------------------------------
template<int DT> struct IO;
template<> struct IO<1> {
    static __device__ __forceinline__ void load8(const void* p, size_t i, float* o) {
        uint4 v = *(const uint4*)((const unsigned short*)p + i);
        const unsigned short* u = (const unsigned short*)&v;
#pragma unroll
        for (int e = 0; e < 8; e++) o[e] = b2f(u[e]);
    }
    static __device__ __forceinline__ float load1(const void* p, size_t i) {
        return b2f(((const unsigned short*)p)[i]);
    }
    static __device__ __forceinline__ void store1(void* p, size_t i, float v) {
        ((unsigned short*)p)[i] = f2b(v);
    }
};
template<> struct IO<0> {
    static __device__ __forceinline__ void load8(const void* p, size_t i, float* o) {
        float4 a = *(const float4*)((const float*)p + i);
        float4 b = *(const float4*)((const float*)p + i + 4);
        o[0]=a.x; o[1]=a.y; o[2]=a.z; o[3]=a.w;
        o[4]=b.x; o[5]=b.y; o[6]=b.z; o[7]=b.w;
    }
    static __device__ __forceinline__ float load1(const void* p, size_t i) {
        return ((const float*)p)[i];
    }
    static __device__ __forceinline__ void store1(void* p, size_t i, float v) {
        ((float*)p)[i] = v;
    }
};

// ---------------------------------------------------------------------------
// Detector: classify x's encoding. flag = 1 (bf16) / 0 (f32).
// ---------------------------------------------------------------------------
__global__ __launch_bounds__(256) void detect_kernel(
    const unsigned int* __restrict__ x, int* __restrict__ flag)
{
    const int t = threadIdx.x;
    int cnt = 0;
    for (int i = t; i < 2048; i += 256) {
        unsigned int e = (x[i] >> 7) & 0xFFu;
        cnt += (e >= 100u && e <= 140u) ? 1 : 0;
    }
#pragma unroll
    for (int off = 32; off; off >>= 1) cnt += __shfl_xor(cnt, off);
    __shared__ int red[4];
    if ((t & 63) == 0) red[t >> 6] = cnt;
    __syncthreads();
    if (t == 0) {
        int tot = red[0] + red[1] + red[2] + red[3];
        flag[0] = (2 * tot > 2048) ? 1 : 0;
    }
}

// ---------------------------------------------------------------------------
// Weight pre-convert: f32 (lds_ stride) -> bf16 (ldd stride, contiguous).
// 8 elems/thread, float4 loads, cvt_pk stores. grid = total/2048.
// ---------------------------------------------------------------------------
template<int PID>
__global__ __launch_bounds__(256) void convw_kernel(
    const int* __restrict__ flag,
    const float* __restrict__ S, int lds_,
    unsigned short* __restrict__ D, int ldd,
    int total)
{
    if (flag[0] != PID) return;
    const int i = (blockIdx.x * 256 + threadIdx.x) * 8;
    if (i >= total) return;
    const int row = i / ldd, col = i - row * ldd;
    const float* sp = S + (size_t)row * lds_ + col;
    float4 f0 = *(const float4*)sp;
    float4 f1 = *(const float4*)(sp + 4);
    uint4 ov;
    ov.x = cvt_pk_bf16(f0.x, f0.y);
    ov.y = cvt_pk_bf16(f0.z, f0.w);
    ov.z = cvt_pk_bf16(f1.x, f1.y);
    ov.w = cvt_pk_bf16(f1.z, f1.w);
    *(uint4*)(D + i) = ov;
}

// ---------------------------------------------------------------------------
// RMSNorm row kernel. X dtype DTX, weight DTW, output always bf16.
// ---------------------------------------------------------------------------
template<int PID, int DTX, int DTW>
__global__ __launch_bounds__(256) void rmsnorm_kernel(
    const int* __restrict__ flag,
    const void* __restrict__ X,
    const void* __restrict__ Wn,
    unsigned short* __restrict__ Out)
{
    if (flag[0] != PID) return;
    const int row = blockIdx.x, t = threadIdx.x;
    float xf[8];
    IO<DTX>::load8(X, (size_t)row * 2048 + t * 8, xf);
    float ss = 0.f;
#pragma unroll
    for (int e = 0; e < 8; e++) ss += xf[e] * xf[e];
#pragma unroll
    for (int off = 32; off; off >>= 1) ss += __shfl_xor(ss, off);
    __shared__ float red[4];
    if ((t & 63) == 0) red[t >> 6] = ss;
    __syncthreads();
    float rr = rsqrtf((red[0] + red[1] + red[2] + red[3]) * (1.0f / 2048.0f) + 1e-6f);
    float wf[8];
    IO<DTW>::load8(Wn, (size_t)t * 8, wf);
    float y[8];
#pragma unroll
    for (int e = 0; e < 8; e++) y[e] = xf[e] * rr * wf[e];
    uint4 ov;
    ov.x = cvt_pk_bf16(y[0], y[1]);
    ov.y = cvt_pk_bf16(y[2], y[3]);
    ov.z = cvt_pk_bf16(y[4], y[5]);
    ov.w = cvt_pk_bf16(y[6], y[7]);
    *(uint4*)(Out + (size_t)row * 2048 + t * 8) = ov;
}

// ---------------------------------------------------------------------------
// gemm8: 256x256 tile, BK=64, 8 waves (512 thr) as 2M x 4N; per-wave 128x64.
// A and W are ALWAYS bf16 (weights pre-converted for DT=0).
// Double-buffered LDS [2][256][64] bf16 per matrix = 128 KiB, XOR swizzle at
// 16B granules (slot s of row r holds granule s^(r&7)).
// Per K-tile: 4 quadrant phases {ds_read frags; setprio(1); 16 MFMA;
// setprio(0); s_barrier}. Staging for T+1 issued in phases 0 (A) / 1 (B)
// into buf^1; single vmcnt(0) at end of phase 3 (~3 phases after issue).
// EPI: 0=store 1=+Res 2=silu 3=*Res.  Res dtype DTR, C dtype DTC.
// ---------------------------------------------------------------------------
#define TBM 256
#define TBN 256
#define TBK 64

template<int PID, int DTR, int DTC, int EPI>
__global__ __launch_bounds__(512, 2) void gemm8(
    const int* __restrict__ flag,
    const unsigned short* __restrict__ A,
    const unsigned short* __restrict__ W, size_t woff, int ldw,
    const void* __restrict__ Res,
    void* __restrict__ C,
    int N, int K, int gx)
{
    if (flag[0] != PID) return;
    __shared__ unsigned short sA[2][TBM * TBK];
    __shared__ unsigned short sB[2][TBN * TBK];

    const int t = threadIdx.x;
    // bijective XCD swizzle (m204): contiguous swz chunk per XCD
    const int nwg = gridDim.x;
    const int q8 = nwg >> 3, r8 = nwg & 7;
    const int xcd = blockIdx.x & 7, o = blockIdx.x >> 3;
    const int swz = (xcd < r8 ? xcd * (q8 + 1) : r8 * (q8 + 1) + (xcd - r8) * q8) + o;
    const int bm = (swz % gx) * TBM;
    const int bn = (swz / gx) * TBN;

    const int w = t >> 6, lane = t & 63, quad = lane >> 4, l16 = lane & 15;
    const int wr = w >> 2, wc = w & 3;
    const int sg = (lane & 7) ^ (lane >> 3);      // pre-swizzled source granule

    const unsigned short* Ab = A + (size_t)(bm + w * 8 + (lane >> 3)) * K + sg * 8;
    const unsigned short* Wb = W + woff + (size_t)(bn + w * 8 + (lane >> 3)) * ldw + sg * 8;
    const int dstb = (w * 8) * TBK;               // wave-uniform LDS row base

    f32x4 acc[8][4];
#pragma unroll
    for (int mi = 0; mi < 8; mi++)
#pragma unroll
        for (int ni = 0; ni < 4; ni++) {
            f32x4 z = {0.f, 0.f, 0.f, 0.f};
            acc[mi][ni] = z;
        }

#define STAGE_A8(b, k0)                                                        \
    {                                                                          \
        _Pragma("unroll")                                                      \
        for (int i = 0; i < 4; i++)                                            \
            gload_lds16(Ab + (size_t)(i * 64) * K + (k0),                      \
                        &sA[b][i * 64 * TBK + dstb]);                          \
    }
#define STAGE_B8(b, k0)                                                        \
    {                                                                          \
        _Pragma("unroll")                                                      \
        for (int i = 0; i < 4; i++)                                            \
            gload_lds16(Wb + (size_t)(i * 64) * ldw + (k0),                    \
                        &sB[b][i * 64 * TBK + dstb]);                          \
    }

    // prologue: stage tile 0 -> buf 0
    STAGE_A8(0, 0)
    STAGE_B8(0, 0)
    asm volatile("s_waitcnt vmcnt(0)" ::: "memory");
    asm volatile("s_barrier" ::: "memory");

    const int NT = K / TBK;
    bf16x8 bfr[4][2];

    for (int T = 0; T < NT; T++) {
        const int buf = T & 1;
        const int k0n = (T + 1) * TBK;
        const bool more = (T + 1 < NT);

        // ---- phase 0: stage A[T+1]; read B-frags (8) + A-quad0; 16 MFMA
        if (more) STAGE_A8(buf ^ 1, k0n)
#pragma unroll
        for (int ni = 0; ni < 4; ni++) {
            const int row = wc * 64 + ni * 16 + l16;
#pragma unroll
            for (int ks = 0; ks < 2; ks++)
                bfr[ni][ks] = *(const bf16x8*)
                    &sB[buf][row * TBK + (((ks * 4 + quad) ^ (row & 7)) * 8)];
        }
        {
            bf16x8 af[2][2];
#pragma unroll
            for (int m2 = 0; m2 < 2; m2++) {
                const int row = wr * 128 + (0 + m2) * 16 + l16;
#pragma unroll
                for (int ks = 0; ks < 2; ks++)
                    af[m2][ks] = *(const bf16x8*)
                        &sA[buf][row * TBK + (((ks * 4 + quad) ^ (row & 7)) * 8)];
            }
            __builtin_amdgcn_s_setprio(1);
#pragma unroll
            for (int m2 = 0; m2 < 2; m2++)
#pragma unroll
                for (int ks = 0; ks < 2; ks++)
#pragma unroll
                    for (int ni = 0; ni < 4; ni++)
                        acc[0 + m2][ni] = __builtin_amdgcn_mfma_f32_16x16x32_bf16(
                            af[m2][ks], bfr[ni][ks], acc[0 + m2][ni], 0, 0, 0);
            __builtin_amdgcn_s_setprio(0);
        }
        asm volatile("s_barrier" ::: "memory");

        // ---- phase 1: stage B[T+1]; A-quad1; 16 MFMA
        if (more) STAGE_B8(buf ^ 1, k0n)
        {
            bf16x8 af[2][2];
#pragma unroll
            for (int m2 = 0; m2 < 2; m2++) {
                const int row = wr * 128 + (2 + m2) * 16 + l16;
#pragma unroll
                for (int ks = 0; ks < 2; ks++)
                    af[m2][ks] = *(const bf16x8*)
                        &sA[buf][row * TBK + (((ks * 4 + quad) ^ (row & 7)) * 8)];
            }
            __builtin_amdgcn_s_setprio(1);
#pragma unroll
            for (int m2 = 0; m2 < 2; m2++)
#pragma unroll
                for (int ks = 0; ks < 2; ks++)
#pragma unroll
                    for (int ni = 0; ni < 4; ni++)
                        acc[2 + m2][ni] = __builtin_amdgcn_mfma_f32_16x16x32_bf16(
                            af[m2][ks], bfr[ni][ks], acc[2 + m2][ni], 0, 0, 0);
            __builtin_amdgcn_s_setprio(0);
        }
        asm volatile("s_barrier" ::: "memory");

        // ---- phase 2: A-quad2; 16 MFMA
        {
            bf16x8 af[2][2];
#pragma unroll
            for (int m2 = 0; m2 < 2; m2++) {
                const int row = wr * 128 + (4 + m2) * 16 + l16;
#pragma unroll
                for (int ks = 0; ks < 2; ks++)
                    af[m2][ks] = *(const bf16x8*)
                        &sA[buf][row * TBK + (((ks * 4 + quad) ^ (row & 7)) * 8)];
            }
            __builtin_amdgcn_s_setprio(1);
#pragma unroll
            for (int m2 = 0; m2 < 2; m2++)
#pragma unroll
                for (int ks = 0; ks < 2; ks++)
#pragma unroll
                    for (int ni = 0; ni < 4; ni++)
                        acc[4 + m2][ni] = __builtin_amdgcn_mfma_f32_16x16x32_bf16(
                            af[m2][ks], bfr[ni][ks], acc[4 + m2][ni], 0, 0, 0);
            __builtin_amdgcn_s_setprio(0);
        }
        asm volatile("s_barrier" ::: "memory");

        // ---- phase 3: A-quad3; 16 MFMA; drain staging; flip
        {
            bf16x8 af[2][2];
#pragma unroll
            for (int m2 = 0; m2 < 2; m2++) {
                const int row = wr * 128 + (6 + m2) * 16 + l16;
#pragma unroll
                for (int ks = 0; ks < 2; ks++)
                    af[m2][ks] = *(const bf16x8*)
                        &sA[buf][row * TBK + (((ks * 4 + quad) ^ (row & 7)) * 8)];
            }
            __builtin_amdgcn_s_setprio(1);
#pragma unroll
            for (int m2 = 0; m2 < 2; m2++)
#pragma unroll
                for (int ks = 0; ks < 2; ks++)
#pragma unroll
                    for (int ni = 0; ni < 4; ni++)
                        acc[6 + m2][ni] = __builtin_amdgcn_mfma_f32_16x16x32_bf16(
                            af[m2][ks], bfr[ni][ks], acc[6 + m2][ni], 0, 0, 0);
            __builtin_amdgcn_s_setprio(0);
        }
        asm volatile("s_waitcnt vmcnt(0)" ::: "memory");
        asm volatile("s_barrier" ::: "memory");
    }
#undef STAGE_A8
#undef STAGE_B8

    // ---- epilogue ----
#pragma unroll
    for (int mi = 0; mi < 8; mi++)
#pragma unroll
        for (int ni = 0; ni < 4; ni++)
#pragma unroll
            for (int r = 0; r < 4; r++) {
                const int row = bm + wr * 128 + mi * 16 + quad * 4 + r;
                const int col = bn + wc * 64 + ni * 16 + l16;
                const size_t idx = (size_t)row * N + col;
                float v = acc[mi][ni][r];
                if constexpr (EPI == 1) v += IO<DTR>::load1(Res, idx);
                if constexpr (EPI == 2) v = v / (1.f + __expf(-v));
                if constexpr (EPI == 3) v *= IO<DTR>::load1(Res, idx);
                IO<DTC>::store1(C, idx, v);
            }
}

// ---------------------------------------------------------------------------
// Flash-style MFMA attention (unchanged from passing round-2 version).
// ---------------------------------------------------------------------------
__device__ __forceinline__ int vt_idx(int d, int kv) {
    return d * 72 + (kv ^ (d & 56));
}

template<int PID>
__global__ __launch_bounds__(256) void attn_kernel(
    const int* __restrict__ flag,
    const unsigned short* __restrict__ QKV,
    unsigned short* __restrict__ O)
{
    if (flag[0] != PID) return;
    __shared__ unsigned short sK[64 * 128];
    __shared__ unsigned short sVt[9280];
    __shared__ unsigned short sP[4][16 * 72];

    const int t = threadIdx.x;
    const int bh = blockIdx.x >> 4;
    const int jj = blockIdx.x & 15;
    const int b = bh >> 4, hh = bh & 15;
    const int w = t >> 6, lane = t & 63, quad = lane >> 4, l16 = lane & 15;

    const unsigned short* Qb = QKV + (size_t)(b * 2048) * 6144 + hh * 128;
    const unsigned short* Kb = Qb + 2048;
    const unsigned short* Vb = Qb + 4096;

    const int str = t >> 4;
    const int stc = (t & 15) * 8;

#pragma unroll
    for (int half = 0; half < 2; half++) {
        const int qt = half ? (31 - jj) : jj;
        const int qbase = qt * 64;

        bf16x8 qf[4];
        {
            const unsigned short* qp = Qb + (size_t)(qbase + w * 16 + l16) * 6144;
#pragma unroll
            for (int ks = 0; ks < 4; ks++)
                qf[ks] = *(const bf16x8*)(qp + ks * 32 + quad * 8);
        }

        float m[4], l[4];
#pragma unroll
        for (int r = 0; r < 4; r++) { m[r] = -1e30f; l[r] = 0.f; }
        f32x4 accO[8];
#pragma unroll
        for (int d0 = 0; d0 < 8; d0++) {
            f32x4 z = {0.f, 0.f, 0.f, 0.f};
            accO[d0] = z;
        }

        for (int tk = 0; tk <= qt; tk++) {
            const int kv0 = tk * 64;
            __syncthreads();
#pragma unroll
            for (int pass = 0; pass < 4; pass++) {
                const int rr = str + pass * 16;
                uint4 kv4 = *(const uint4*)(Kb + (size_t)(kv0 + rr) * 6144 + stc);
                *(uint4*)&sK[(rr * 128 + stc) ^ ((rr & 7) << 3)] = kv4;
                uint4 vv4 = *(const uint4*)(Vb + (size_t)(kv0 + rr) * 6144 + stc);
                const unsigned short* vu = (const unsigned short*)&vv4;
#pragma unroll
                for (int e = 0; e < 8; e++)
                    sVt[vt_idx(stc + e, rr)] = vu[e];
            }
            __syncthreads();

            const bool diag = (tk == qt);
            f32x4 s[4];
#pragma unroll
            for (int nf = 0; nf < 4; nf++) {
                f32x4 z = {0.f, 0.f, 0.f, 0.f};
                s[nf] = z;
                if (!(diag && nf > w)) {
#pragma unroll
                    for (int ks = 0; ks < 4; ks++) {
                        const int row = nf * 16 + l16;
                        bf16x8 kf = *(const bf16x8*)
                            &sK[(row * 128 + ks * 32 + quad * 8) ^ ((row & 7) << 3)];
                        s[nf] = __builtin_amdgcn_mfma_f32_16x16x32_bf16(qf[ks], kf, s[nf], 0, 0, 0);
                    }
                }
#pragma unroll
                for (int r = 0; r < 4; r++) s[nf][r] *= 0.08838834764831845f;
            }
            if (diag) {
#pragma unroll
                for (int nf = 0; nf < 4; nf++)
#pragma unroll
                    for (int r = 0; r < 4; r++)
                        if (nf * 16 + l16 > w * 16 + quad * 4 + r) s[nf][r] = -1e30f;
            }

            float alpha[4], rs[4];
#pragma unroll
            for (int r = 0; r < 4; r++) {
                float v = fmaxf(fmaxf(s[0][r], s[1][r]), fmaxf(s[2][r], s[3][r]));
                v = fmaxf(v, __shfl_xor(v, 1));
                v = fmaxf(v, __shfl_xor(v, 2));
                v = fmaxf(v, __shfl_xor(v, 4));
                v = fmaxf(v, __shfl_xor(v, 8));
                float mn = fmaxf(m[r], v);
                alpha[r] = __expf(m[r] - mn);
                m[r] = mn;
                rs[r] = 0.f;
            }
#pragma unroll
            for (int nf = 0; nf < 4; nf++)
#pragma unroll
                for (int r = 0; r < 4; r++) {
                    float p = __expf(s[nf][r] - m[r]);
                    rs[r] += p;
                    sP[w][(quad * 4 + r) * 72 + nf * 16 + l16] = f2b(p);
                }
#pragma unroll
            for (int r = 0; r < 4; r++) {
                float sum = rs[r];
                sum += __shfl_xor(sum, 1);
                sum += __shfl_xor(sum, 2);
                sum += __shfl_xor(sum, 4);
                sum += __shfl_xor(sum, 8);
                l[r] = l[r] * alpha[r] + sum;
            }
#pragma unroll
            for (int d0 = 0; d0 < 8; d0++)
#pragma unroll
                for (int r = 0; r < 4; r++) accO[d0][r] *= alpha[r];

#pragma unroll
            for (int ks = 0; ks < 2; ks++) {
                bf16x8 pa = *(const bf16x8*)&sP[w][l16 * 72 + ks * 32 + quad * 8];
#pragma unroll
                for (int d0 = 0; d0 < 8; d0++) {
                    bf16x8 vb = *(const bf16x8*)
                        &sVt[vt_idx(d0 * 16 + l16, ks * 32 + quad * 8)];
                    accO[d0] = __builtin_amdgcn_mfma_f32_16x16x32_bf16(pa, vb, accO[d0], 0, 0, 0);
                }
            }
        }

        float linv[4];
#pragma unroll
        for (int r = 0; r < 4; r++) linv[r] = 1.0f / l[r];
        unsigned short* Op = O + (size_t)(b * 2048 + qbase + w * 16) * 2048 + hh * 128;
#pragma unroll
        for (int d0 = 0; d0 < 8; d0++)
#pragma unroll
            for (int r = 0; r < 4; r++)
                Op[(size_t)(quad * 4 + r) * 2048 + d0 * 16 + l16] =
                    f2b(accO[d0][r] * linv[r]);
    }
}

// ---------------------------------------------------------------------------
template<int DT>
static void run_pipeline(const void* x, const void* n1w, const void* qkvw,
                         const void* outw, const void* n2w, const void* gatew,
                         const void* upw, const void* downw,
                         void* outp, char* ws, const int* flag, hipStream_t stream)
{
    const size_t MB = 1024 * 1024;
    unsigned short* qkv = (unsigned short*)(ws);            // [0,48)
    unsigned short* x2  = (unsigned short*)(ws);            // [0,16) after qkv dead
    unsigned short* h2  = (unsigned short*)(ws + 16 * MB);  // [16,32)
    unsigned short* a   = (unsigned short*)(ws + 32 * MB);  // [32,64)
    unsigned short* h   = (unsigned short*)(ws + 48 * MB);  // [48,64)
    unsigned short* o   = (unsigned short*)(ws + 48 * MB);  // [48,64) after h dead

    // 1) h = rmsnorm(x, w1)
    rmsnorm_kernel<DT, DT, DT><<<4096, 256, 0, stream>>>(flag, x, n1w, h);

    if constexpr (DT == 1) {
        const unsigned short* Wq = (const unsigned short*)qkvw;
        const unsigned short* Wo = (const unsigned short*)outw;
        const unsigned short* Wg = (const unsigned short*)gatew;
        const unsigned short* Wu = (const unsigned short*)upw;
        const unsigned short* Wd = (const unsigned short*)downw;
        gemm8<1, 1, 1, 0><<<384, 512, 0, stream>>>(
            flag, h, Wq, 0, 2048, nullptr, qkv, 6144, 2048, 16);
        attn_kernel<1><<<512, 256, 0, stream>>>(flag, qkv, o);
        gemm8<1, 1, 1, 1><<<128, 512, 0, stream>>>(
            flag, o, Wo, 0, 2048, x, x2, 2048, 2048, 16);
        rmsnorm_kernel<1, 1, 1><<<4096, 256, 0, stream>>>(flag, x2, n2w, h2);
        gemm8<1, 1, 1, 2><<<256, 512, 0, stream>>>(
            flag, h2, Wg, 0, 2048, nullptr, a, 4096, 2048, 16);
        gemm8<1, 1, 1, 3><<<256, 512, 0, stream>>>(
            flag, h2, Wu, 0, 2048, a, a, 4096, 2048, 16);
        gemm8<1, 1, 1, 1><<<128, 512, 0, stream>>>(
            flag, a, Wd, 0, 8192, x2, x2, 2048, 4096, 16);
        gemm8<1, 1, 1, 2><<<256, 512, 0, stream>>>(
            flag, h2, Wg, (size_t)4096 * 2048, 2048, nullptr, a, 4096, 2048, 16);
        gemm8<1, 1, 1, 3><<<256, 512, 0, stream>>>(
            flag, h2, Wu, (size_t)4096 * 2048, 2048, a, a, 4096, 2048, 16);
        gemm8<1, 1, 1, 1><<<128, 512, 0, stream>>>(
            flag, a, Wd, 4096, 8192, x2, outp, 2048, 4096, 16);
    } else {
        // DT=0: pre-convert each f32 weight panel to bf16, then pure-bf16 GEMMs.
        // Scratch: d_out (free until final GEMM writes it); last down chunk
        // converts into the then-dead h2 region.
        unsigned short* WC  = (unsigned short*)outp;   // up to 25.2 MB used
        unsigned short* WC2 = h2;                      // [16,32) for last chunk

        // qkv (6144x2048)
        convw_kernel<0><<<6144, 256, 0, stream>>>(
            flag, (const float*)qkvw, 2048, WC, 2048, 6144 * 2048);
        gemm8<0, 1, 1, 0><<<384, 512, 0, stream>>>(
            flag, h, WC, 0, 2048, nullptr, qkv, 6144, 2048, 16);
        attn_kernel<0><<<512, 256, 0, stream>>>(flag, qkv, o);
        // out (2048x2048); Res = x (f32)
        convw_kernel<0><<<2048, 256, 0, stream>>>(
            flag, (const float*)outw, 2048, WC, 2048, 2048 * 2048);
        gemm8<0, 0, 1, 1><<<128, 512, 0, stream>>>(
            flag, o, WC, 0, 2048, x, x2, 2048, 2048, 16);
        rmsnorm_kernel<0, 1, 0><<<4096, 256, 0, stream>>>(flag, x2, n2w, h2);
        // FF chunk 0
        convw_kernel<0><<<4096, 256, 0, stream>>>(
            flag, (const float*)gatew, 2048, WC, 2048, 4096 * 2048);
        gemm8<0, 1, 1, 2><<<256, 512, 0, stream>>>(
            flag, h2, WC, 0, 2048, nullptr, a, 4096, 2048, 16);
        convw_kernel<0><<<4096, 256, 0, stream>>>(
            flag, (const float*)upw, 2048, WC, 2048, 4096 * 2048);
        gemm8<0, 1, 1, 3><<<256, 512, 0, stream>>>(
            flag, h2, WC, 0, 2048, a, a, 4096, 2048, 16);
        convw_kernel<0><<<4096, 256, 0, stream>>>(
            flag, (const float*)downw, 8192, WC, 4096, 2048 * 4096);
        gemm8<0, 1, 1, 1><<<128, 512, 0, stream>>>(
            flag, a, WC, 0, 4096, x2, x2, 2048, 4096, 16);
        // FF chunk 1
        convw_kernel<0><<<4096, 256, 0, stream>>>(
            flag, (const float*)gatew + (size_t)4096 * 2048, 2048, WC, 2048, 4096 * 2048);
        gemm8<0, 1, 1, 2><<<256, 512, 0, stream>>>(
            flag, h2, WC, 0, 2048, nullptr, a, 4096, 2048, 16);
        convw_kernel<0><<<4096, 256, 0, stream>>>(
            flag, (const float*)upw + (size_t)4096 * 2048, 2048, WC, 2048, 4096 * 2048);
        gemm8<0, 1, 1, 3><<<256, 512, 0, stream>>>(
            flag, h2, WC, 0, 2048, a, a, 4096, 2048, 16);
        // down chunk 1 -> h2 region (h2 dead after the up GEMM above);
        // final GEMM writes f32 output into d_out.
        convw_kernel<0><<<4096, 256, 0, stream>>>(
            flag, (const float*)downw + 4096, 8192, WC2, 4096, 2048 * 4096);
        gemm8<0, 1, 0, 1><<<128, 512, 0, stream>>>(
            flag, a, WC2, 0, 4096, x2, outp, 2048, 4096, 16);
    }
}

extern "C" void kernel_launch(void* const* d_in, const int* in_sizes, int n_in,
                              void* d_out, int out_size, void* d_ws, size_t ws_size,
                              hipStream_t stream)
{
    const void* x      = d_in[0];
    // d_in[1] = causal mask: implemented analytically, unused
    const void* n1w    = d_in[2];
    const void* qkv_w  = d_in[3];
    const void* out_w  = d_in[4];
    const void* n2w    = d_in[5];
    const void* gate_w = d_in[6];
    const void* up_w   = d_in[7];
    const void* down_w = d_in[8];

    char* ws = (char*)d_ws;
    const size_t MB = 1024 * 1024;
    size_t flag_off = 64 * MB;
    if (ws_size < flag_off + 4) flag_off = (ws_size - 4) & ~(size_t)3;
    int* flag = (int*)(ws + flag_off);

    detect_kernel<<<1, 256, 0, stream>>>((const unsigned int*)x, flag);
    run_pipeline<0>(x, n1w, qkv_w, out_w, n2w, gate_w, up_w, down_w,
                    d_out, ws, flag, stream);
    run_pipeline<1>(x, n1w, qkv_w, out_w, n2w, gate_w, up_w, down_w,
                    d_out, ws, flag, stream);
}

// Round 7
// 1294.131 us; speedup vs baseline: 1.0616x; 1.0616x over previous
//
#include <hip/hip_runtime.h>

// ---------------------------------------------------------------------------
// TransformerBlock: B=2, L=2048, D=2048, H=16, HD=128, FF=8192.
// Dual-dtype (runtime-detected): DT=0 (f32 I/O — ACTIVE path per rocprof) and
// DT=1 (bf16 I/O); detector writes flag; kernels no-op unless flag==PID.
// DT=0 pre-converts each f32 weight panel to bf16 (convw_kernel) into scratch
// (d_out until the final GEMM, h2-region for the last down chunk).
// All GEMMs: gemm3 — BK=32, TRIPLE-buffered LDS, 2-K-tile prefetch lead,
// counted s_waitcnt vmcnt(N) (never 0 in steady state), ONE barrier per
// K-tile, setprio around the 32-MFMA cluster. Tiles: 256x256 (1 blk/CU) for
// N>=4096 GEMMs, 128x256 for N=2048 GEMMs (grid=256 -> full GPU).
// Workspace (64MB + flag word): qkv[0,48) / x2[0,16) / h2[16,32) / a[32,64)
//   h,o[48,64); flag at min(64MB, ws_size-4). d_out doubles as weight scratch.
// ---------------------------------------------------------------------------

typedef __attribute__((ext_vector_type(8))) short bf16x8;
typedef __attribute__((ext_vector_type(4))) float f32x4;

__device__ __forceinline__ float b2f(unsigned short u) {
    return __uint_as_float(((unsigned int)u) << 16);
}
__device__ __forceinline__ unsigned short f2b(float f) {
    unsigned int i = __float_as_uint(f);
    i += 0x7fffu + ((i >> 16) & 1u);   // RNE
    return (unsigned short)(i >> 16);
}
// packed f32x2 -> bf16x2 (RNE), single VALU op; no builtin on gfx950
__device__ __forceinline__ unsigned int cvt_pk_bf16(float lo, float hi) {
    unsigned int r;
    asm("v_cvt_pk_bf16_f32 %0, %1, %2" : "=v"(r) : "v"(lo), "v"(hi));
    return r;
}

// async global->LDS, 16 B per lane; LDS dest is wave-uniform base + lane*16.
__device__ __forceinline__ void gload_lds16(const unsigned short* g, unsigned short* l) {
    __builtin_amdgcn_global_load_lds(
        (const __attribute__((address_space(1))) unsigned int*)g,
        (__attribute__((address_space(3))) unsigned int*)l,
        16, 0, 0);
}

// ---- typed I/O helpers: DT=1 bf16, DT=0 f32 -------------------------------
template<int DT> struct IO;
template<> struct IO<1> {
    static __device__ __forceinline__ void load8(const void* p, size_t i, float* o) {
        uint4 v = *(const uint4*)((const unsigned short*)p + i);
        const unsigned short* u = (const unsigned short*)&v;
#pragma unroll
        for (int e = 0; e < 8; e++) o[e] = b2f(u[e]);
    }
    static __device__ __forceinline__ float load1(const void* p, size_t i) {
        return b2f(((const unsigned short*)p)[i]);
    }
    static __device__ __forceinline__ void store1(void* p, size_t i, float v) {
        ((unsigned short*)p)[i] = f2b(v);
    }
};
template<> struct IO<0> {
    static __device__ __forceinline__ void load8(const void* p, size_t i, float* o) {
        float4 a = *(const float4*)((const float*)p + i);
        float4 b = *(const float4*)((const float*)p + i + 4);
        o[0]=a.x; o[1]=a.y; o[2]=a.z; o[3]=a.w;
        o[4]=b.x; o[5]=b.y; o[6]=b.z; o[7]=b.w;
    }
    static __device__ __forceinline__ float load1(const void* p, size_t i) {
        return ((const float*)p)[i];
    }
    static __device__ __forceinline__ void store1(void* p, size_t i, float v) {
        ((float*)p)[i] = v;
    }
};

// ---------------------------------------------------------------------------
// Detector: classify x's encoding. flag = 1 (bf16) / 0 (f32).
// ---------------------------------------------------------------------------
__global__ __launch_bounds__(256) void detect_kernel(
    const unsigned int* __restrict__ x, int* __restrict__ flag)
{
    const int t = threadIdx.x;
    int cnt = 0;
    for (int i = t; i < 2048; i += 256) {
        unsigned int e = (x[i] >> 7) & 0xFFu;
        cnt += (e >= 100u && e <= 140u) ? 1 : 0;
    }
#pragma unroll
    for (int off = 32; off; off >>= 1) cnt += __shfl_xor(cnt, off);
    __shared__ int red[4];
    if ((t & 63) == 0) red[t >> 6] = cnt;
    __syncthreads();
    if (t == 0) {
        int tot = red[0] + red[1] + red[2] + red[3];
        flag[0] = (2 * tot > 2048) ? 1 : 0;
    }
}

// ---------------------------------------------------------------------------
// Weight pre-convert: f32 (lds_ stride) -> bf16 (ldd stride, contiguous).
// ---------------------------------------------------------------------------
template<int PID>
__global__ __launch_bounds__(256) void convw_kernel(
    const int* __restrict__ flag,
    const float* __restrict__ S, int lds_,
    unsigned short* __restrict__ D, int ldd,
    int total)
{
    if (flag[0] != PID) return;
    const int i = (blockIdx.x * 256 + threadIdx.x) * 8;
    if (i >= total) return;
    const int row = i / ldd, col = i - row * ldd;
    const float* sp = S + (size_t)row * lds_ + col;
    float4 f0 = *(const float4*)sp;
    float4 f1 = *(const float4*)(sp + 4);
    uint4 ov;
    ov.x = cvt_pk_bf16(f0.x, f0.y);
    ov.y = cvt_pk_bf16(f0.z, f0.w);
    ov.z = cvt_pk_bf16(f1.x, f1.y);
    ov.w = cvt_pk_bf16(f1.z, f1.w);
    *(uint4*)(D + i) = ov;
}

// ---------------------------------------------------------------------------
// RMSNorm row kernel. X dtype DTX, weight DTW, output always bf16.
// ---------------------------------------------------------------------------
template<int PID, int DTX, int DTW>
__global__ __launch_bounds__(256) void rmsnorm_kernel(
    const int* __restrict__ flag,
    const void* __restrict__ X,
    const void* __restrict__ Wn,
    unsigned short* __restrict__ Out)
{
    if (flag[0] != PID) return;
    const int row = blockIdx.x, t = threadIdx.x;
    float xf[8];
    IO<DTX>::load8(X, (size_t)row * 2048 + t * 8, xf);
    float ss = 0.f;
#pragma unroll
    for (int e = 0; e < 8; e++) ss += xf[e] * xf[e];
#pragma unroll
    for (int off = 32; off; off >>= 1) ss += __shfl_xor(ss, off);
    __shared__ float red[4];
    if ((t & 63) == 0) red[t >> 6] = ss;
    __syncthreads();
    float rr = rsqrtf((red[0] + red[1] + red[2] + red[3]) * (1.0f / 2048.0f) + 1e-6f);
    float wf[8];
    IO<DTW>::load8(Wn, (size_t)t * 8, wf);
    float y[8];
#pragma unroll
    for (int e = 0; e < 8; e++) y[e] = xf[e] * rr * wf[e];
    uint4 ov;
    ov.x = cvt_pk_bf16(y[0], y[1]);
    ov.y = cvt_pk_bf16(y[2], y[3]);
    ov.z = cvt_pk_bf16(y[4], y[5]);
    ov.w = cvt_pk_bf16(y[6], y[7]);
    *(uint4*)(Out + (size_t)row * 2048 + t * 8) = ov;
}

// ---------------------------------------------------------------------------
// gemm3: C(M,N) = A(M,K)bf16 @ W(N,ldw)bf16^T [+ epilogue].
// Tile TBMX x 256, BK=32. 8 waves (512 thr) as 2M x 4N; per-wave TBMX/2 x 64.
// LDS: TRIPLE-buffered [3][TBMX*32] + [3][256*32] bf16 (96KB / 72KB).
// Swizzle: slot s of row r holds 16B-granule s ^ ((r ^ (r>>2)) & 3)
//   -> ds_read_b128 fragments are <=2-way on banks (free); staging writes
//   are linear (lane*16B) with pre-swizzled global source granule.
// Schedule per K-tile T (2-tile prefetch lead, counted vmcnt):
//   s_waitcnt vmcnt(LPT)   // tile T complete; tile T+1's LPT loads in flight
//   s_barrier              // publishes T; buffer (T+2)%3 readers are done
//   stage tile T+2 -> buf (T+2)%3
//   ds_read frags from buf T%3; setprio(1); MF*4 MFMA; setprio(0)
// Last tile peeled to vmcnt(0). One barrier per K-tile, no other drains.
// EPI: 0=store 1=+Res 2=silu 3=*Res.  Res dtype DTR, C dtype DTC.
// ---------------------------------------------------------------------------
template<int PID, int TBMX, int DTR, int DTC, int EPI>
__global__ __launch_bounds__(512, 2) void gemm3(
    const int* __restrict__ flag,
    const unsigned short* __restrict__ A,
    const unsigned short* __restrict__ W, size_t woff, int ldw,
    const void* __restrict__ Res,
    void* __restrict__ C,
    int N, int K, int gx)
{
    if (flag[0] != PID) return;
    constexpr int MF  = TBMX / 32;     // A fragments per wave (8 or 4)
    constexpr int ACH = TBMX / 128;    // A staging chunks (2 or 1)
    constexpr int LPT = ACH + 2;       // loads/thread per K-tile
    __shared__ unsigned short sA[3][TBMX * 32];
    __shared__ unsigned short sB[3][256 * 32];

    const int t = threadIdx.x;
    // bijective XCD swizzle (m204)
    const int nwg = gridDim.x;
    const int q8 = nwg >> 3, r8 = nwg & 7;
    const int xcd = blockIdx.x & 7, oo = blockIdx.x >> 3;
    const int swz = (xcd < r8 ? xcd * (q8 + 1) : r8 * (q8 + 1) + (xcd - r8) * q8) + oo;
    const int bm = (swz % gx) * TBMX;
    const int bn = (swz / gx) * 256;

    const int w = t >> 6, lane = t & 63, quad = lane >> 4, l16 = lane & 15;
    const int wr = w >> 2, wc = w & 3;
    const int swr = (l16 ^ (l16 >> 2)) & 3;          // row-swizzle at read

    // staging: thread t covers local row c*128 + w*16 + (lane>>2), slot t&3;
    // source granule = (t&3) ^ sw(row) = (t&3) ^ ((lane>>2)&3) ^ quad.
    const int srow = w * 16 + (lane >> 2);
    const int sgr  = (((t & 3) ^ ((lane >> 2) & 3) ^ quad) << 3);
    const unsigned short* Abase = A + (size_t)(bm + srow) * K + sgr;
    const unsigned short* Wbase = W + woff + (size_t)(bn + srow) * ldw + sgr;
    const int ldst = w * 512;          // wave-uniform elem offset in 4096-chunk

    f32x4 acc[MF][4];
#pragma unroll
    for (int mi = 0; mi < MF; mi++)
#pragma unroll
        for (int ni = 0; ni < 4; ni++) {
            f32x4 z = {0.f, 0.f, 0.f, 0.f};
            acc[mi][ni] = z;
        }

#define STG(bb, T)                                                             \
    do {                                                                       \
        const size_t ko = (size_t)(T) * 32;                                    \
        _Pragma("unroll")                                                      \
        for (int c = 0; c < ACH; c++)                                          \
            gload_lds16(Abase + (size_t)(c * 128) * K + ko,                    \
                        &sA[bb][c * 4096 + ldst]);                             \
        _Pragma("unroll")                                                      \
        for (int c = 0; c < 2; c++)                                            \
            gload_lds16(Wbase + (size_t)(c * 128) * ldw + ko,                  \
                        &sB[bb][c * 4096 + ldst]);                             \
    } while (0)

    // prologue: 2-tile lead
    STG(0, 0);
    STG(1, 1);

    const int NT = K / 32;
    for (int T = 0; T < NT; T++) {
        if (T + 1 < NT) {
            if constexpr (LPT == 4)
                asm volatile("s_waitcnt vmcnt(4)" ::: "memory");
            else
                asm volatile("s_waitcnt vmcnt(3)" ::: "memory");
        } else {
            asm volatile("s_waitcnt vmcnt(0)" ::: "memory");
        }
        asm volatile("s_barrier" ::: "memory");
        if (T + 2 < NT) STG((T + 2) % 3, T + 2);

        const unsigned short* a_ = sA[T % 3];
        const unsigned short* b_ = sB[T % 3];
        bf16x8 af[MF], bfr[4];
#pragma unroll
        for (int ni = 0; ni < 4; ni++) {
            const int row = wc * 64 + ni * 16 + l16;
            bfr[ni] = *(const bf16x8*)&b_[row * 32 + ((quad ^ swr) << 3)];
        }
#pragma unroll
        for (int mi = 0; mi < MF; mi++) {
            const int row = wr * (TBMX / 2) + mi * 16 + l16;
            af[mi] = *(const bf16x8*)&a_[row * 32 + ((quad ^ swr) << 3)];
        }
        __builtin_amdgcn_s_setprio(1);
#pragma unroll
        for (int mi = 0; mi < MF; mi++)
#pragma unroll
            for (int ni = 0; ni < 4; ni++)
                acc[mi][ni] = __builtin_amdgcn_mfma_f32_16x16x32_bf16(
                    af[mi], bfr[ni], acc[mi][ni], 0, 0, 0);
        __builtin_amdgcn_s_setprio(0);
    }
#undef STG

    // ---- epilogue ----
#pragma unroll
    for (int mi = 0; mi < MF; mi++)
#pragma unroll
        for (int ni = 0; ni < 4; ni++)
#pragma unroll
            for (int r = 0; r < 4; r++) {
                const int row = bm + wr * (TBMX / 2) + mi * 16 + quad * 4 + r;
                const int col = bn + wc * 64 + ni * 16 + l16;
                const size_t idx = (size_t)row * N + col;
                float v = acc[mi][ni][r];
                if constexpr (EPI == 1) v += IO<DTR>::load1(Res, idx);
                if constexpr (EPI == 2) v = v / (1.f + __expf(-v));
                if constexpr (EPI == 3) v *= IO<DTR>::load1(Res, idx);
                IO<DTC>::store1(C, idx, v);
            }
}

// ---------------------------------------------------------------------------
// Flash-style MFMA attention (unchanged from passing round-2 version).
// ---------------------------------------------------------------------------
__device__ __forceinline__ int vt_idx(int d, int kv) {
    return d * 72 + (kv ^ (d & 56));
}

template<int PID>
__global__ __launch_bounds__(256) void attn_kernel(
    const int* __restrict__ flag,
    const unsigned short* __restrict__ QKV,
    unsigned short* __restrict__ O)
{
    if (flag[0] != PID) return;
    __shared__ unsigned short sK[64 * 128];
    __shared__ unsigned short sVt[9280];
    __shared__ unsigned short sP[4][16 * 72];

    const int t = threadIdx.x;
    const int bh = blockIdx.x >> 4;
    const int jj = blockIdx.x & 15;
    const int b = bh >> 4, hh = bh & 15;
    const int w = t >> 6, lane = t & 63, quad = lane >> 4, l16 = lane & 15;

    const unsigned short* Qb = QKV + (size_t)(b * 2048) * 6144 + hh * 128;
    const unsigned short* Kb = Qb + 2048;
    const unsigned short* Vb = Qb + 4096;

    const int str = t >> 4;
    const int stc = (t & 15) * 8;

#pragma unroll
    for (int half = 0; half < 2; half++) {
        const int qt = half ? (31 - jj) : jj;
        const int qbase = qt * 64;

        bf16x8 qf[4];
        {
            const unsigned short* qp = Qb + (size_t)(qbase + w * 16 + l16) * 6144;
#pragma unroll
            for (int ks = 0; ks < 4; ks++)
                qf[ks] = *(const bf16x8*)(qp + ks * 32 + quad * 8);
        }

        float m[4], l[4];
#pragma unroll
        for (int r = 0; r < 4; r++) { m[r] = -1e30f; l[r] = 0.f; }
        f32x4 accO[8];
#pragma unroll
        for (int d0 = 0; d0 < 8; d0++) {
            f32x4 z = {0.f, 0.f, 0.f, 0.f};
            accO[d0] = z;
        }

        for (int tk = 0; tk <= qt; tk++) {
            const int kv0 = tk * 64;
            __syncthreads();
#pragma unroll
            for (int pass = 0; pass < 4; pass++) {
                const int rr = str + pass * 16;
                uint4 kv4 = *(const uint4*)(Kb + (size_t)(kv0 + rr) * 6144 + stc);
                *(uint4*)&sK[(rr * 128 + stc) ^ ((rr & 7) << 3)] = kv4;
                uint4 vv4 = *(const uint4*)(Vb + (size_t)(kv0 + rr) * 6144 + stc);
                const unsigned short* vu = (const unsigned short*)&vv4;
#pragma unroll
                for (int e = 0; e < 8; e++)
                    sVt[vt_idx(stc + e, rr)] = vu[e];
            }
            __syncthreads();

            const bool diag = (tk == qt);
            f32x4 s[4];
#pragma unroll
            for (int nf = 0; nf < 4; nf++) {
                f32x4 z = {0.f, 0.f, 0.f, 0.f};
                s[nf] = z;
                if (!(diag && nf > w)) {
#pragma unroll
                    for (int ks = 0; ks < 4; ks++) {
                        const int row = nf * 16 + l16;
                        bf16x8 kf = *(const bf16x8*)
                            &sK[(row * 128 + ks * 32 + quad * 8) ^ ((row & 7) << 3)];
                        s[nf] = __builtin_amdgcn_mfma_f32_16x16x32_bf16(qf[ks], kf, s[nf], 0, 0, 0);
                    }
                }
#pragma unroll
                for (int r = 0; r < 4; r++) s[nf][r] *= 0.08838834764831845f;
            }
            if (diag) {
#pragma unroll
                for (int nf = 0; nf < 4; nf++)
#pragma unroll
                    for (int r = 0; r < 4; r++)
                        if (nf * 16 + l16 > w * 16 + quad * 4 + r) s[nf][r] = -1e30f;
            }

            float alpha[4], rs[4];
#pragma unroll
            for (int r = 0; r < 4; r++) {
                float v = fmaxf(fmaxf(s[0][r], s[1][r]), fmaxf(s[2][r], s[3][r]));
                v = fmaxf(v, __shfl_xor(v, 1));
                v = fmaxf(v, __shfl_xor(v, 2));
                v = fmaxf(v, __shfl_xor(v, 4));
                v = fmaxf(v, __shfl_xor(v, 8));
                float mn = fmaxf(m[r], v);
                alpha[r] = __expf(m[r] - mn);
                m[r] = mn;
                rs[r] = 0.f;
            }
#pragma unroll
            for (int nf = 0; nf < 4; nf++)
#pragma unroll
                for (int r = 0; r < 4; r++) {
                    float p = __expf(s[nf][r] - m[r]);
                    rs[r] += p;
                    sP[w][(quad * 4 + r) * 72 + nf * 16 + l16] = f2b(p);
                }
#pragma unroll
            for (int r = 0; r < 4; r++) {
                float sum = rs[r];
                sum += __shfl_xor(sum, 1);
                sum += __shfl_xor(sum, 2);
                sum += __shfl_xor(sum, 4);
                sum += __shfl_xor(sum, 8);
                l[r] = l[r] * alpha[r] + sum;
            }
#pragma unroll
            for (int d0 = 0; d0 < 8; d0++)
#pragma unroll
                for (int r = 0; r < 4; r++) accO[d0][r] *= alpha[r];

#pragma unroll
            for (int ks = 0; ks < 2; ks++) {
                bf16x8 pa = *(const bf16x8*)&sP[w][l16 * 72 + ks * 32 + quad * 8];
#pragma unroll
                for (int d0 = 0; d0 < 8; d0++) {
                    bf16x8 vb = *(const bf16x8*)
                        &sVt[vt_idx(d0 * 16 + l16, ks * 32 + quad * 8)];
                    accO[d0] = __builtin_amdgcn_mfma_f32_16x16x32_bf16(pa, vb, accO[d0], 0, 0, 0);
                }
            }
        }

        float linv[4];
#pragma unroll
        for (int r = 0; r < 4; r++) linv[r] = 1.0f / l[r];
        unsigned short* Op = O + (size_t)(b * 2048 + qbase + w * 16) * 2048 + hh * 128;
#pragma unroll
        for (int d0 = 0; d0 < 8; d0++)
#pragma unroll
            for (int r = 0; r < 4; r++)
                Op[(size_t)(quad * 4 + r) * 2048 + d0 * 16 + l16] =
                    f2b(accO[d0][r] * linv[r]);
    }
}

// ---------------------------------------------------------------------------
template<int DT>
static void run_pipeline(const void* x, const void* n1w, const void* qkvw,
                         const void* outw, const void* n2w, const void* gatew,
                         const void* upw, const void* downw,
                         void* outp, char* ws, const int* flag, hipStream_t stream)
{
    const size_t MB = 1024 * 1024;
    unsigned short* qkv = (unsigned short*)(ws);            // [0,48)
    unsigned short* x2  = (unsigned short*)(ws);            // [0,16) after qkv dead
    unsigned short* h2  = (unsigned short*)(ws + 16 * MB);  // [16,32)
    unsigned short* a   = (unsigned short*)(ws + 32 * MB);  // [32,64)
    unsigned short* h   = (unsigned short*)(ws + 48 * MB);  // [48,64)
    unsigned short* o   = (unsigned short*)(ws + 48 * MB);  // [48,64) after h dead

    // 1) h = rmsnorm(x, w1)
    rmsnorm_kernel<DT, DT, DT><<<4096, 256, 0, stream>>>(flag, x, n1w, h);

    if constexpr (DT == 1) {
        const unsigned short* Wq = (const unsigned short*)qkvw;
        const unsigned short* Wo = (const unsigned short*)outw;
        const unsigned short* Wg = (const unsigned short*)gatew;
        const unsigned short* Wu = (const unsigned short*)upw;
        const unsigned short* Wd = (const unsigned short*)downw;
        gemm3<1, 256, 1, 1, 0><<<384, 512, 0, stream>>>(
            flag, h, Wq, 0, 2048, nullptr, qkv, 6144, 2048, 16);
        attn_kernel<1><<<512, 256, 0, stream>>>(flag, qkv, o);
        gemm3<1, 128, 1, 1, 1><<<256, 512, 0, stream>>>(
            flag, o, Wo, 0, 2048, x, x2, 2048, 2048, 32);
        rmsnorm_kernel<1, 1, 1><<<4096, 256, 0, stream>>>(flag, x2, n2w, h2);
        gemm3<1, 256, 1, 1, 2><<<256, 512, 0, stream>>>(
            flag, h2, Wg, 0, 2048, nullptr, a, 4096, 2048, 16);
        gemm3<1, 256, 1, 1, 3><<<256, 512, 0, stream>>>(
            flag, h2, Wu, 0, 2048, a, a, 4096, 2048, 16);
        gemm3<1, 128, 1, 1, 1><<<256, 512, 0, stream>>>(
            flag, a, Wd, 0, 8192, x2, x2, 2048, 4096, 32);
        gemm3<1, 256, 1, 1, 2><<<256, 512, 0, stream>>>(
            flag, h2, Wg, (size_t)4096 * 2048, 2048, nullptr, a, 4096, 2048, 16);
        gemm3<1, 256, 1, 1, 3><<<256, 512, 0, stream>>>(
            flag, h2, Wu, (size_t)4096 * 2048, 2048, a, a, 4096, 2048, 16);
        gemm3<1, 128, 1, 1, 1><<<256, 512, 0, stream>>>(
            flag, a, Wd, 4096, 8192, x2, outp, 2048, 4096, 32);
    } else {
        // DT=0: pre-convert each f32 weight panel to bf16, then bf16 GEMMs.
        unsigned short* WC  = (unsigned short*)outp;   // scratch until final
        unsigned short* WC2 = h2;                      // last chunk scratch

        convw_kernel<0><<<6144, 256, 0, stream>>>(
            flag, (const float*)qkvw, 2048, WC, 2048, 6144 * 2048);
        gemm3<0, 256, 1, 1, 0><<<384, 512, 0, stream>>>(
            flag, h, WC, 0, 2048, nullptr, qkv, 6144, 2048, 16);
        attn_kernel<0><<<512, 256, 0, stream>>>(flag, qkv, o);
        convw_kernel<0><<<2048, 256, 0, stream>>>(
            flag, (const float*)outw, 2048, WC, 2048, 2048 * 2048);
        gemm3<0, 128, 0, 1, 1><<<256, 512, 0, stream>>>(
            flag, o, WC, 0, 2048, x, x2, 2048, 2048, 32);
        rmsnorm_kernel<0, 1, 0><<<4096, 256, 0, stream>>>(flag, x2, n2w, h2);
        // FF chunk 0
        convw_kernel<0><<<4096, 256, 0, stream>>>(
            flag, (const float*)gatew, 2048, WC, 2048, 4096 * 2048);
        gemm3<0, 256, 1, 1, 2><<<256, 512, 0, stream>>>(
            flag, h2, WC, 0, 2048, nullptr, a, 4096, 2048, 16);
        convw_kernel<0><<<4096, 256, 0, stream>>>(
            flag, (const float*)upw, 2048, WC, 2048, 4096 * 2048);
        gemm3<0, 256, 1, 1, 3><<<256, 512, 0, stream>>>(
            flag, h2, WC, 0, 2048, a, a, 4096, 2048, 16);
        convw_kernel<0><<<4096, 256, 0, stream>>>(
            flag, (const float*)downw, 8192, WC, 4096, 2048 * 4096);
        gemm3<0, 128, 1, 1, 1><<<256, 512, 0, stream>>>(
            flag, a, WC, 0, 4096, x2, x2, 2048, 4096, 32);
        // FF chunk 1
        convw_kernel<0><<<4096, 256, 0, stream>>>(
            flag, (const float*)gatew + (size_t)4096 * 2048, 2048, WC, 2048, 4096 * 2048);
        gemm3<0, 256, 1, 1, 2><<<256, 512, 0, stream>>>(
            flag, h2, WC, 0, 2048, nullptr, a, 4096, 2048, 16);
        convw_kernel<0><<<4096, 256, 0, stream>>>(
            flag, (const float*)upw + (size_t)4096 * 2048, 2048, WC, 2048, 4096 * 2048);
        gemm3<0, 256, 1, 1, 3><<<256, 512, 0, stream>>>(
            flag, h2, WC, 0, 2048, a, a, 4096, 2048, 16);
        // last down chunk: conv into h2 region (dead), write f32 to d_out
        convw_kernel<0><<<4096, 256, 0, stream>>>(
            flag, (const float*)downw + 4096, 8192, WC2, 4096, 2048 * 4096);
        gemm3<0, 128, 1, 0, 1><<<256, 512, 0, stream>>>(
            flag, a, WC2, 0, 4096, x2, outp, 2048, 4096, 32);
    }
}

extern "C" void kernel_launch(void* const* d_in, const int* in_sizes, int n_in,
                              void* d_out, int out_size, void* d_ws, size_t ws_size,
                              hipStream_t stream)
{
    const void* x      = d_in[0];
    // d_in[1] = causal mask: implemented analytically, unused
    const void* n1w    = d_in[2];
    const void* qkv_w  = d_in[3];
    const void* out_w  = d_in[4];
    const void* n2w    = d_in[5];
    const void* gate_w = d_in[6];
    const void* up_w   = d_in[7];
    const void* down_w = d_in[8];

    char* ws = (char*)d_ws;
    const size_t MB = 1024 * 1024;
    size_t flag_off = 64 * MB;
    if (ws_size < flag_off + 4) flag_off = (ws_size - 4) & ~(size_t)3;
    int* flag = (int*)(ws + flag_off);

    detect_kernel<<<1, 256, 0, stream>>>((const unsigned int*)x, flag);
    run_pipeline<0>(x, n1w, qkv_w, out_w, n2w, gate_w, up_w, down_w,
                    d_out, ws, flag, stream);
    run_pipeline<1>(x, n1w, qkv_w, out_w, n2w, gate_w, up_w, down_w,
                    d_out, ws, flag, stream);
}

// Round 9
// 1170.866 us; speedup vs baseline: 1.1733x; 1.1053x over previous
//
#include <hip/hip_runtime.h>

// ---------------------------------------------------------------------------
// TransformerBlock: B=2, L=2048, D=2048, H=16, HD=128, FF=8192.
// Dual-dtype (runtime-detected): DT=0 (f32 I/O — ACTIVE path per rocprof) and
// DT=1 (bf16 I/O); detector writes flag; kernels no-op unless flag==PID.
// DT=0 pre-converts each f32 weight panel to bf16 (convw_kernel) into scratch
// (d_out until the final GEMM, h2-region for the last down chunk).
// All GEMMs: gemm_bt — the m97-class 128x128/BKK=64 structure (256 thr,
// 32KiB LDS -> 4-5 blocks/CU wave overlap, granule-XOR swizzle = 0 bank
// conflicts, global_load_lds both sides). Rounds 6-7 established that
// 512-thr/1-block-CU phase schedules lose the cross-block overlap and stall
// at ~24% MfmaUtil; this structure is the measured-best.
// Workspace (64MB + flag word): qkv[0,48) / x2[0,16) / h2[16,32) / a[32,64)
//   h,o[48,64); flag at min(64MB, ws_size-4). d_out doubles as weight scratch.
// ---------------------------------------------------------------------------

typedef __attribute__((ext_vector_type(8))) short bf16x8;
typedef __attribute__((ext_vector_type(4))) float f32x4;

__device__ __forceinline__ float b2f(unsigned short u) {
    return __uint_as_float(((unsigned int)u) << 16);
}
__device__ __forceinline__ unsigned short f2b(float f) {
    unsigned int i = __float_as_uint(f);
    i += 0x7fffu + ((i >> 16) & 1u);   // RNE
    return (unsigned short)(i >> 16);
}
// packed f32x2 -> bf16x2 (RNE), single VALU op; no builtin on gfx950
__device__ __forceinline__ unsigned int cvt_pk_bf16(float lo, float hi) {
    unsigned int r;
    asm("v_cvt_pk_bf16_f32 %0, %1, %2" : "=v"(r) : "v"(lo), "v"(hi));
    return r;
}

// async global->LDS, 16 B per lane; LDS dest is wave-uniform base + lane*16.
__device__ __forceinline__ void gload_lds16(const unsigned short* g, unsigned short* l) {
    __builtin_amdgcn_global_load_lds(
        (const __attribute__((address_space(1))) unsigned int*)g,
        (__attribute__((address_space(3))) unsigned int*)l,
        16, 0, 0);
}

// ---- typed I/O helpers: DT=1 bf16, DT=0 f32 -------------------------------
template<int DT> struct IO;
template<> struct IO<1> {
    static __device__ __forceinline__ void load8(const void* p, size_t i, float* o) {
        uint4 v = *(const uint4*)((const unsigned short*)p + i);
        const unsigned short* u = (const unsigned short*)&v;
#pragma unroll
        for (int e = 0; e < 8; e++) o[e] = b2f(u[e]);
    }
    static __device__ __forceinline__ float load1(const void* p, size_t i) {
        return b2f(((const unsigned short*)p)[i]);
    }
    static __device__ __forceinline__ void store1(void* p, size_t i, float v) {
        ((unsigned short*)p)[i] = f2b(v);
    }
};
template<> struct IO<0> {
    static __device__ __forceinline__ void load8(const void* p, size_t i, float* o) {
        float4 a = *(const float4*)((const float*)p + i);
        float4 b = *(const float4*)((const float*)p + i + 4);
        o[0]=a.x; o[1]=a.y; o[2]=a.z; o[3]=a.w;
        o[4]=b.x; o[5]=b.y; o[6]=b.z; o[7]=b.w;
    }
    static __device__ __forceinline__ float load1(const void* p, size_t i) {
        return ((const float*)p)[i];
    }
    static __device__ __forceinline__ void store1(void* p, size_t i, float v) {
        ((float*)p)[i] = v;
    }
};

// ---------------------------------------------------------------------------
// Detector: classify x's encoding. flag = 1 (bf16) / 0 (f32).
// ---------------------------------------------------------------------------
__global__ __launch_bounds__(256) void detect_kernel(
    const unsigned int* __restrict__ x, int* __restrict__ flag)
{
    const int t = threadIdx.x;
    int cnt = 0;
    for (int i = t; i < 2048; i += 256) {
        unsigned int e = (x[i] >> 7) & 0xFFu;
        cnt += (e >= 100u && e <= 140u) ? 1 : 0;
    }
#pragma unroll
    for (int off = 32; off; off >>= 1) cnt += __shfl_xor(cnt, off);
    __shared__ int red[4];
    if ((t & 63) == 0) red[t >> 6] = cnt;
    __syncthreads();
    if (t == 0) {
        int tot = red[0] + red[1] + red[2] + red[3];
        flag[0] = (2 * tot > 2048) ? 1 : 0;
    }
}

// ---------------------------------------------------------------------------
// Weight pre-convert: f32 (lds_ stride) -> bf16 (ldd stride, contiguous).
// ---------------------------------------------------------------------------
template<int PID>
__global__ __launch_bounds__(256) void convw_kernel(
    const int* __restrict__ flag,
    const float* __restrict__ S, int lds_,
    unsigned short* __restrict__ D, int ldd,
    int total)
{
    if (flag[0] != PID) return;
    const int i = (blockIdx.x * 256 + threadIdx.x) * 8;
    if (i >= total) return;
    const int row = i / ldd, col = i - row * ldd;
    const float* sp = S + (size_t)row * lds_ + col;
    float4 f0 = *(const float4*)sp;
    float4 f1 = *(const float4*)(sp + 4);
    uint4 ov;
    ov.x = cvt_pk_bf16(f0.x, f0.y);
    ov.y = cvt_pk_bf16(f0.z, f0.w);
    ov.z = cvt_pk_bf16(f1.x, f1.y);
    ov.w = cvt_pk_bf16(f1.z, f1.w);
    *(uint4*)(D + i) = ov;
}

// ---------------------------------------------------------------------------
// RMSNorm row kernel. X dtype DTX, weight DTW, output always bf16.
// ---------------------------------------------------------------------------
template<int PID, int DTX, int DTW>
__global__ __launch_bounds__(256) void rmsnorm_kernel(
    const int* __restrict__ flag,
    const void* __restrict__ X,
    const void* __restrict__ Wn,
    unsigned short* __restrict__ Out)
{
    if (flag[0] != PID) return;
    const int row = blockIdx.x, t = threadIdx.x;
    float xf[8];
    IO<DTX>::load8(X, (size_t)row * 2048 + t * 8, xf);
    float ss = 0.f;
#pragma unroll
    for (int e = 0; e < 8; e++) ss += xf[e] * xf[e];
#pragma unroll
    for (int off = 32; off; off >>= 1) ss += __shfl_xor(ss, off);
    __shared__ float red[4];
    if ((t & 63) == 0) red[t >> 6] = ss;
    __syncthreads();
    float rr = rsqrtf((red[0] + red[1] + red[2] + red[3]) * (1.0f / 2048.0f) + 1e-6f);
    float wf[8];
    IO<DTW>::load8(Wn, (size_t)t * 8, wf);
    float y[8];
#pragma unroll
    for (int e = 0; e < 8; e++) y[e] = xf[e] * rr * wf[e];
    uint4 ov;
    ov.x = cvt_pk_bf16(y[0], y[1]);
    ov.y = cvt_pk_bf16(y[2], y[3]);
    ov.z = cvt_pk_bf16(y[4], y[5]);
    ov.w = cvt_pk_bf16(y[6], y[7]);
    *(uint4*)(Out + (size_t)row * 2048 + t * 8) = ov;
}

// ---------------------------------------------------------------------------
// GEMM (m97-class, proven): C(M,N) = A(M,K)bf16 @ W(N,ldw)bf16^T [+ epilogue].
// 128x128 tile, BKK=64, 4 waves x (4x4) mfma_16x16x32_bf16 (64x64 per wave).
// Grid: x = M-tiles (consecutive blocks share the B tile -> L2 reuse).
// LDS: linear [128][64] per matrix (128B rows), XOR-swizzled at 16B granules:
//   slot s of row r holds granule s ^ (r&7) -> ds_read_b128 conflict-free
//   (measured 0 in rounds 3-6). Both A and W staged via global_load_lds
//   (dest linear, SOURCE granule pre-swizzled). Weights are ALWAYS bf16 here
//   (DT=0 pre-converts via convw_kernel).
// EPI: 0=store, 1=+Res store, 2=silu store, 3=*Res store.
// ---------------------------------------------------------------------------
#define BM 128
#define BN 128
#define BKK 64

template<int PID, int DTR, int DTC, int EPI>
__global__ __launch_bounds__(256) void gemm_bt(
    const int* __restrict__ flag,
    const unsigned short* __restrict__ A,
    const unsigned short* __restrict__ W, size_t woff, int ldw,
    const void* __restrict__ Res,
    void* __restrict__ C,
    int N, int K)
{
    if (flag[0] != PID) return;
    __shared__ unsigned short sA[BM * BKK];
    __shared__ unsigned short sB[BN * BKK];
    const int t = threadIdx.x;
    const int bm = blockIdx.x * BM, bn = blockIdx.y * BN;
    const int w = t >> 6, lane = t & 63, quad = lane >> 4, l16 = lane & 15;
    const int wm = (w & 1) * 64, wn = (w >> 1) * 64;

    const int srow = lane >> 3;               // row within 8-row issue group
    const int sg   = (lane & 7) ^ srow;       // pre-swizzled source granule

    f32x4 acc[4][4];
#pragma unroll
    for (int mi = 0; mi < 4; mi++)
#pragma unroll
        for (int ni = 0; ni < 4; ni++) {
            f32x4 z = {0.f, 0.f, 0.f, 0.f};
            acc[mi][ni] = z;
        }

    for (int k0 = 0; k0 < K; k0 += BKK) {
        // ---- stage A + W (both bf16, async direct-to-LDS) ----
#pragma unroll
        for (int i = 0; i < 4; i++) {
            const int r0 = w * 32 + i * 8;
            gload_lds16(A + (size_t)(bm + r0 + srow) * K + k0 + sg * 8,
                        &sA[r0 * BKK]);
        }
#pragma unroll
        for (int i = 0; i < 4; i++) {
            const int r0 = w * 32 + i * 8;
            gload_lds16(W + woff + (size_t)(bn + r0 + srow) * ldw + k0 + sg * 8,
                        &sB[r0 * BKK]);
        }
        __syncthreads();   // drains vmcnt(0): LDS tiles complete

        // ---- compute: 2 k-subtiles x 16 mfma ----
#pragma unroll
        for (int ks = 0; ks < 2; ks++) {
            bf16x8 af[4], bfr[4];
#pragma unroll
            for (int mi = 0; mi < 4; mi++) {
                const int r = wm + mi * 16 + l16;
                af[mi] = *(const bf16x8*)
                    &sA[r * BKK + (((ks * 4 + quad) ^ (r & 7)) * 8)];
            }
#pragma unroll
            for (int ni = 0; ni < 4; ni++) {
                const int r = wn + ni * 16 + l16;
                bfr[ni] = *(const bf16x8*)
                    &sB[r * BKK + (((ks * 4 + quad) ^ (r & 7)) * 8)];
            }
#pragma unroll
            for (int mi = 0; mi < 4; mi++)
#pragma unroll
                for (int ni = 0; ni < 4; ni++)
                    acc[mi][ni] = __builtin_amdgcn_mfma_f32_16x16x32_bf16(
                        af[mi], bfr[ni], acc[mi][ni], 0, 0, 0);
        }
        __syncthreads();
    }

#pragma unroll
    for (int mi = 0; mi < 4; mi++)
#pragma unroll
        for (int ni = 0; ni < 4; ni++)
#pragma unroll
            for (int r = 0; r < 4; r++) {
                const int row = bm + wm + mi * 16 + quad * 4 + r;
                const int col = bn + wn + ni * 16 + l16;
                const size_t idx = (size_t)row * N + col;
                float v = acc[mi][ni][r];
                if constexpr (EPI == 1) v += IO<DTR>::load1(Res, idx);
                if constexpr (EPI == 2) v = v / (1.f + __expf(-v));
                if constexpr (EPI == 3) v *= IO<DTR>::load1(Res, idx);
                IO<DTC>::store1(C, idx, v);
            }
}

// ---------------------------------------------------------------------------
// Flash-style MFMA attention (unchanged from passing round-2 version).
// ---------------------------------------------------------------------------
__device__ __forceinline__ int vt_idx(int d, int kv) {
    return d * 72 + (kv ^ (d & 56));
}

template<int PID>
__global__ __launch_bounds__(256) void attn_kernel(
    const int* __restrict__ flag,
    const unsigned short* __restrict__ QKV,
    unsigned short* __restrict__ O)
{
    if (flag[0] != PID) return;
    __shared__ unsigned short sK[64 * 128];
    __shared__ unsigned short sVt[9280];
    __shared__ unsigned short sP[4][16 * 72];

    const int t = threadIdx.x;
    const int bh = blockIdx.x >> 4;
    const int jj = blockIdx.x & 15;
    const int b = bh >> 4, hh = bh & 15;
    const int w = t >> 6, lane = t & 63, quad = lane >> 4, l16 = lane & 15;

    const unsigned short* Qb = QKV + (size_t)(b * 2048) * 6144 + hh * 128;
    const unsigned short* Kb = Qb + 2048;
    const unsigned short* Vb = Qb + 4096;

    const int str = t >> 4;
    const int stc = (t & 15) * 8;

#pragma unroll
    for (int half = 0; half < 2; half++) {
        const int qt = half ? (31 - jj) : jj;
        const int qbase = qt * 64;

        bf16x8 qf[4];
        {
            const unsigned short* qp = Qb + (size_t)(qbase + w * 16 + l16) * 6144;
#pragma unroll
            for (int ks = 0; ks < 4; ks++)
                qf[ks] = *(const bf16x8*)(qp + ks * 32 + quad * 8);
        }

        float m[4], l[4];
#pragma unroll
        for (int r = 0; r < 4; r++) { m[r] = -1e30f; l[r] = 0.f; }
        f32x4 accO[8];
#pragma unroll
        for (int d0 = 0; d0 < 8; d0++) {
            f32x4 z = {0.f, 0.f, 0.f, 0.f};
            accO[d0] = z;
        }

        for (int tk = 0; tk <= qt; tk++) {
            const int kv0 = tk * 64;
            __syncthreads();
#pragma unroll
            for (int pass = 0; pass < 4; pass++) {
                const int rr = str + pass * 16;
                uint4 kv4 = *(const uint4*)(Kb + (size_t)(kv0 + rr) * 6144 + stc);
                *(uint4*)&sK[(rr * 128 + stc) ^ ((rr & 7) << 3)] = kv4;
                uint4 vv4 = *(const uint4*)(Vb + (size_t)(kv0 + rr) * 6144 + stc);
                const unsigned short* vu = (const unsigned short*)&vv4;
#pragma unroll
                for (int e = 0; e < 8; e++)
                    sVt[vt_idx(stc + e, rr)] = vu[e];
            }
            __syncthreads();

            const bool diag = (tk == qt);
            f32x4 s[4];
#pragma unroll
            for (int nf = 0; nf < 4; nf++) {
                f32x4 z = {0.f, 0.f, 0.f, 0.f};
                s[nf] = z;
                if (!(diag && nf > w)) {
#pragma unroll
                    for (int ks = 0; ks < 4; ks++) {
                        const int row = nf * 16 + l16;
                        bf16x8 kf = *(const bf16x8*)
                            &sK[(row * 128 + ks * 32 + quad * 8) ^ ((row & 7) << 3)];
                        s[nf] = __builtin_amdgcn_mfma_f32_16x16x32_bf16(qf[ks], kf, s[nf], 0, 0, 0);
                    }
                }
#pragma unroll
                for (int r = 0; r < 4; r++) s[nf][r] *= 0.08838834764831845f;
            }
            if (diag) {
#pragma unroll
                for (int nf = 0; nf < 4; nf++)
#pragma unroll
                    for (int r = 0; r < 4; r++)
                        if (nf * 16 + l16 > w * 16 + quad * 4 + r) s[nf][r] = -1e30f;
            }

            float alpha[4], rs[4];
#pragma unroll
            for (int r = 0; r < 4; r++) {
                float v = fmaxf(fmaxf(s[0][r], s[1][r]), fmaxf(s[2][r], s[3][r]));
                v = fmaxf(v, __shfl_xor(v, 1));
                v = fmaxf(v, __shfl_xor(v, 2));
                v = fmaxf(v, __shfl_xor(v, 4));
                v = fmaxf(v, __shfl_xor(v, 8));
                float mn = fmaxf(m[r], v);
                alpha[r] = __expf(m[r] - mn);
                m[r] = mn;
                rs[r] = 0.f;
            }
#pragma unroll
            for (int nf = 0; nf < 4; nf++)
#pragma unroll
                for (int r = 0; r < 4; r++) {
                    float p = __expf(s[nf][r] - m[r]);
                    rs[r] += p;
                    sP[w][(quad * 4 + r) * 72 + nf * 16 + l16] = f2b(p);
                }
#pragma unroll
            for (int r = 0; r < 4; r++) {
                float sum = rs[r];
                sum += __shfl_xor(sum, 1);
                sum += __shfl_xor(sum, 2);
                sum += __shfl_xor(sum, 4);
                sum += __shfl_xor(sum, 8);
                l[r] = l[r] * alpha[r] + sum;
            }
#pragma unroll
            for (int d0 = 0; d0 < 8; d0++)
#pragma unroll
                for (int r = 0; r < 4; r++) accO[d0][r] *= alpha[r];

#pragma unroll
            for (int ks = 0; ks < 2; ks++) {
                bf16x8 pa = *(const bf16x8*)&sP[w][l16 * 72 + ks * 32 + quad * 8];
#pragma unroll
                for (int d0 = 0; d0 < 8; d0++) {
                    bf16x8 vb = *(const bf16x8*)
                        &sVt[vt_idx(d0 * 16 + l16, ks * 32 + quad * 8)];
                    accO[d0] = __builtin_amdgcn_mfma_f32_16x16x32_bf16(pa, vb, accO[d0], 0, 0, 0);
                }
            }
        }

        float linv[4];
#pragma unroll
        for (int r = 0; r < 4; r++) linv[r] = 1.0f / l[r];
        unsigned short* Op = O + (size_t)(b * 2048 + qbase + w * 16) * 2048 + hh * 128;
#pragma unroll
        for (int d0 = 0; d0 < 8; d0++)
#pragma unroll
            for (int r = 0; r < 4; r++)
                Op[(size_t)(quad * 4 + r) * 2048 + d0 * 16 + l16] =
                    f2b(accO[d0][r] * linv[r]);
    }
}

// ---------------------------------------------------------------------------
template<int DT>
static void run_pipeline(const void* x, const void* n1w, const void* qkvw,
                         const void* outw, const void* n2w, const void* gatew,
                         const void* upw, const void* downw,
                         void* outp, char* ws, const int* flag, hipStream_t stream)
{
    const size_t MB = 1024 * 1024;
    unsigned short* qkv = (unsigned short*)(ws);            // [0,48)
    unsigned short* x2  = (unsigned short*)(ws);            // [0,16) after qkv dead
    unsigned short* h2  = (unsigned short*)(ws + 16 * MB);  // [16,32)
    unsigned short* a   = (unsigned short*)(ws + 32 * MB);  // [32,64)
    unsigned short* h   = (unsigned short*)(ws + 48 * MB);  // [48,64)
    unsigned short* o   = (unsigned short*)(ws + 48 * MB);  // [48,64) after h dead

    // 1) h = rmsnorm(x, w1)
    rmsnorm_kernel<DT, DT, DT><<<4096, 256, 0, stream>>>(flag, x, n1w, h);

    if constexpr (DT == 1) {
        const unsigned short* Wq = (const unsigned short*)qkvw;
        const unsigned short* Wo = (const unsigned short*)outw;
        const unsigned short* Wg = (const unsigned short*)gatew;
        const unsigned short* Wu = (const unsigned short*)upw;
        const unsigned short* Wd = (const unsigned short*)downw;
        gemm_bt<1, 1, 1, 0><<<dim3(32, 48), 256, 0, stream>>>(
            flag, h, Wq, 0, 2048, nullptr, qkv, 6144, 2048);
        attn_kernel<1><<<512, 256, 0, stream>>>(flag, qkv, o);
        gemm_bt<1, 1, 1, 1><<<dim3(32, 16), 256, 0, stream>>>(
            flag, o, Wo, 0, 2048, x, x2, 2048, 2048);
        rmsnorm_kernel<1, 1, 1><<<4096, 256, 0, stream>>>(flag, x2, n2w, h2);
        gemm_bt<1, 1, 1, 2><<<dim3(32, 32), 256, 0, stream>>>(
            flag, h2, Wg, 0, 2048, nullptr, a, 4096, 2048);
        gemm_bt<1, 1, 1, 3><<<dim3(32, 32), 256, 0, stream>>>(
            flag, h2, Wu, 0, 2048, a, a, 4096, 2048);
        gemm_bt<1, 1, 1, 1><<<dim3(32, 16), 256, 0, stream>>>(
            flag, a, Wd, 0, 8192, x2, x2, 2048, 4096);
        gemm_bt<1, 1, 1, 2><<<dim3(32, 32), 256, 0, stream>>>(
            flag, h2, Wg, (size_t)4096 * 2048, 2048, nullptr, a, 4096, 2048);
        gemm_bt<1, 1, 1, 3><<<dim3(32, 32), 256, 0, stream>>>(
            flag, h2, Wu, (size_t)4096 * 2048, 2048, a, a, 4096, 2048);
        gemm_bt<1, 1, 1, 1><<<dim3(32, 16), 256, 0, stream>>>(
            flag, a, Wd, 4096, 8192, x2, outp, 2048, 4096);
    } else {
        // DT=0: pre-convert each f32 weight panel to bf16, then bf16 GEMMs.
        unsigned short* WC  = (unsigned short*)outp;   // scratch until final
        unsigned short* WC2 = h2;                      // last chunk scratch

        convw_kernel<0><<<6144, 256, 0, stream>>>(
            flag, (const float*)qkvw, 2048, WC, 2048, 6144 * 2048);
        gemm_bt<0, 1, 1, 0><<<dim3(32, 48), 256, 0, stream>>>(
            flag, h, WC, 0, 2048, nullptr, qkv, 6144, 2048);
        attn_kernel<0><<<512, 256, 0, stream>>>(flag, qkv, o);
        convw_kernel<0><<<2048, 256, 0, stream>>>(
            flag, (const float*)outw, 2048, WC, 2048, 2048 * 2048);
        gemm_bt<0, 0, 1, 1><<<dim3(32, 16), 256, 0, stream>>>(
            flag, o, WC, 0, 2048, x, x2, 2048, 2048);
        rmsnorm_kernel<0, 1, 0><<<4096, 256, 0, stream>>>(flag, x2, n2w, h2);
        // FF chunk 0
        convw_kernel<0><<<4096, 256, 0, stream>>>(
            flag, (const float*)gatew, 2048, WC, 2048, 4096 * 2048);
        gemm_bt<0, 1, 1, 2><<<dim3(32, 32), 256, 0, stream>>>(
            flag, h2, WC, 0, 2048, nullptr, a, 4096, 2048);
        convw_kernel<0><<<4096, 256, 0, stream>>>(
            flag, (const float*)upw, 2048, WC, 2048, 4096 * 2048);
        gemm_bt<0, 1, 1, 3><<<dim3(32, 32), 256, 0, stream>>>(
            flag, h2, WC, 0, 2048, a, a, 4096, 2048);
        convw_kernel<0><<<4096, 256, 0, stream>>>(
            flag, (const float*)downw, 8192, WC, 4096, 2048 * 4096);
        gemm_bt<0, 1, 1, 1><<<dim3(32, 16), 256, 0, stream>>>(
            flag, a, WC, 0, 4096, x2, x2, 2048, 4096);
        // FF chunk 1
        convw_kernel<0><<<4096, 256, 0, stream>>>(
            flag, (const float*)gatew + (size_t)4096 * 2048, 2048, WC, 2048, 4096 * 2048);
        gemm_bt<0, 1, 1, 2><<<dim3(32, 32), 256, 0, stream>>>(
            flag, h2, WC, 0, 2048, nullptr, a, 4096, 2048);
        convw_kernel<0><<<4096, 256, 0, stream>>>(
            flag, (const float*)upw + (size_t)4096 * 2048, 2048, WC, 2048, 4096 * 2048);
        gemm_bt<0, 1, 1, 3><<<dim3(32, 32), 256, 0, stream>>>(
            flag, h2, WC, 0, 2048, a, a, 4096, 2048);
        // last down chunk: conv into h2 region (dead), write f32 to d_out
        convw_kernel<0><<<4096, 256, 0, stream>>>(
            flag, (const float*)downw + 4096, 8192, WC2, 4096, 2048 * 4096);
        gemm_bt<0, 1, 0, 1><<<dim3(32, 16), 256, 0, stream>>>(
            flag, a, WC2, 0, 4096, x2, outp, 2048, 4096);
    }
}

extern "C" void kernel_launch(void* const* d_in, const int* in_sizes, int n_in,
                              void* d_out, int out_size, void* d_ws, size_t ws_size,
                              hipStream_t stream)
{
    const void* x      = d_in[0];
    // d_in[1] = causal mask: implemented analytically, unused
    const void* n1w    = d_in[2];
    const void* qkv_w  = d_in[3];
    const void* out_w  = d_in[4];
    const void* n2w    = d_in[5];
    const void* gate_w = d_in[6];
    const void* up_w   = d_in[7];
    const void* down_w = d_in[8];

    char* ws = (char*)d_ws;
    const size_t MB = 1024 * 1024;
    size_t flag_off = 64 * MB;
    if (ws_size < flag_off + 4) flag_off = (ws_size - 4) & ~(size_t)3;
    int* flag = (int*)(ws + flag_off);

    detect_kernel<<<1, 256, 0, stream>>>((const unsigned int*)x, flag);
    run_pipeline<0>(x, n1w, qkv_w, out_w, n2w, gate_w, up_w, down_w,
                    d_out, ws, flag, stream);
    run_pipeline<1>(x, n1w, qkv_w, out_w, n2w, gate_w, up_w, down_w,
                    d_out, ws, flag, stream);
}